// Round 6
// baseline (210.769 us; speedup 1.0000x reference)
//
#include <hip/hip_runtime.h>
#include <math.h>

// LinOSS layer (IM), fused MFMA pipeline v3. Bt=16, L=4096, H=128, P=256.
//   k_prep : coeffs, bf16 weight frags (B, C'), and w_k = M^k s table (64/p)
//   k_sum  : per (b,chunk): GEMM1 -> in-register weighted reduce = chunk-final
//            (no serial scan, no BUX). -> loc
//   k_scanB: cross-chunk recombination via Mchunk=M^64 -> per-chunk inits
//   k_pass2: sequential halves through single 32KB BUX: GEMM1 -> scan from
//            init (in-place x2 bf16) -> GEMM2 partial; epilogue +in*D.
//            LDS 48KB -> 3 blocks/CU.

constexpr int BTc = 16;
constexpr int Lc  = 4096;
constexpr int Hc  = 128;
constexpr int Pc  = 256;
constexpr int CL  = 64;
constexpr int NC  = Lc / CL;   // 64
constexpr int LOG2CL = 6;

typedef __attribute__((ext_vector_type(8))) short short8;
typedef __attribute__((ext_vector_type(4))) float f32x4;

// workspace byte offsets
constexpr size_t CF_OFF  = 0;                   // 10*256 floats
constexpr size_t BF_OFF  = 16384;               // 65536 bf16 GEMM1 B frags
constexpr size_t CFR_OFF = BF_OFF  + 131072;    // 65536 bf16 GEMM2 C' frags
constexpr size_t W_OFF   = CFR_OFF + 131072;    // 256*64 float2 w-table
constexpr size_t LOC_OFF = W_OFF   + 131072;    // 16*64*512 float2 (4 MB)
constexpr size_t INI_OFF = LOC_OFF + 4194304;   // 4 MB

// k_pass2 LDS: U bf16 [64][128] swz (16KB) | BUX bf16 [64][256] swz (32KB)
constexpr int LDS_U   = 0;
constexpr int LDS_BUX = 16384;
constexpr int LDS2_BYTES = 49152;
// k_sum LDS: U (16KB) | part float2 [2][256] (4KB)
constexpr int LDS_PART = 16384;
constexpr int LDSS_BYTES = 20480;

__device__ __forceinline__ unsigned short f2bf(float x) {
    unsigned u = __float_as_uint(x);
    u += 0x7fffu + ((u >> 16) & 1u);          // RNE
    return (unsigned short)(u >> 16);
}
__device__ __forceinline__ float bf2f(unsigned short h) {
    return __uint_as_float(((unsigned)h) << 16);
}
__device__ __forceinline__ f32x4 mfma16(short8 a, short8 b, f32x4 c) {
    return __builtin_amdgcn_mfma_f32_16x16x32_bf16(a, b, c, 0, 0, 0);
}
__device__ __forceinline__ int swz(int l) { return (l ^ (l >> 3)) & 7; }

// ---------------------------------------------------------------- prep
__global__ __launch_bounds__(256) void k_prep(const float* __restrict__ A_diag,
                                              const float* __restrict__ steps,
                                              const float* __restrict__ Bw,
                                              const float* __restrict__ Cw,
                                              float* __restrict__ cf,
                                              unsigned short* __restrict__ BF,
                                              unsigned short* __restrict__ CFr,
                                              float2* __restrict__ W) {
    int idx = blockIdx.x * 256 + threadIdx.x;   // 0..65535
    {   // GEMM1 B fragments: col n = 2p+part (512), k = h (128)
        int j = idx & 7, lane = (idx >> 3) & 63, nfg = (idx >> 9) & 31, kt = idx >> 14;
        int k = kt * 32 + (lane >> 4) * 8 + j;
        int n = nfg * 16 + (lane & 15);
        int p = n >> 1, part = n & 1;
        BF[idx] = f2bf(Bw[(p * Hc + k) * 2 + part]);
    }
    {   // GEMM2 C' fragments: col h (128), k = channel 2p+part (512), -ci on im
        int j = idx & 7, lane = (idx >> 3) & 63, nfg = (idx >> 9) & 7, ktG = idx >> 12;
        int k = ktG * 32 + (lane >> 4) * 8 + j;
        int h = nfg * 16 + (lane & 15);
        int p = k >> 1, part = k & 1;
        float v = Cw[(h * Pc + p) * 2 + part];
        CFr[idx] = f2bf(part ? -v : v);
    }
    if (blockIdx.x == 0) {
        int p = threadIdx.x;
        float a  = fmaxf(A_diag[p], 0.0f);
        float st = 1.0f / (1.0f + expf(-steps[p]));
        float s2a   = st * st * a;
        float schur = 1.0f / (1.0f + s2a);
        float m11 = 1.0f - s2a * schur;
        float m12 = -st * a * schur;
        float m21 = st * schur;
        float m22 = schur;
        cf[0*Pc+p] = m11;  cf[1*Pc+p] = m12;
        cf[2*Pc+p] = m21;  cf[3*Pc+p] = m22;
        float s1 = m11 * st, s2 = m21 * st;
        cf[4*Pc+p] = s1;
        cf[5*Pc+p] = s2;
        // w_k = M^k (s1,s2), k = 0..63
        float w1 = s1, w2 = s2;
        for (int k = 0; k < CL; k++) {
            W[p * CL + k] = make_float2(w1, w2);
            float t1 = fmaf(m11, w1, m12 * w2);
            float t2 = fmaf(m21, w1, m22 * w2);
            w1 = t1; w2 = t2;
        }
        // Mchunk = M^64 by repeated squaring
        float a11=m11, a12=m12, a21=m21, a22=m22;
        #pragma unroll
        for (int i = 0; i < LOG2CL; i++) {
            float b11 = a11*a11 + a12*a21;
            float b12 = a11*a12 + a12*a22;
            float b21 = a21*a11 + a22*a21;
            float b22 = a21*a12 + a22*a22;
            a11=b11; a12=b12; a21=b21; a22=b22;
        }
        cf[6*Pc+p]=a11; cf[7*Pc+p]=a12; cf[8*Pc+p]=a21; cf[9*Pc+p]=a22;
    }
}

// ---------------------------------------------------------------- scan B
__global__ __launch_bounds__(512) void k_scanB(const float* __restrict__ cf,
                                               const float2* __restrict__ loc,
                                               float2* __restrict__ ini) {
    int b = blockIdx.x, n = threadIdx.x;
    int p = n >> 1;
    float A11=cf[6*Pc+p], A12=cf[7*Pc+p], A21=cf[8*Pc+p], A22=cf[9*Pc+p];
    float x1 = 0.f, x2 = 0.f;
    for (int g = 0; g < 8; g++) {
        float2 lv[8];
        #pragma unroll
        for (int j = 0; j < 8; j++)
            lv[j] = loc[((size_t)(b * NC + g * 8 + j)) * 512 + n];
        #pragma unroll
        for (int j = 0; j < 8; j++) {
            size_t idx = ((size_t)(b * NC + g * 8 + j)) * 512 + n;
            ini[idx] = make_float2(x1, x2);
            float n1 = fmaf(A11, x1, fmaf(A12, x2, lv[j].x));
            float n2 = fmaf(A21, x1, fmaf(A22, x2, lv[j].y));
            x1 = n1; x2 = n2;
        }
    }
}

// ---------------------------------------------------------------- stage U helper
__device__ __forceinline__ void stage_U(char* sm, const float* __restrict__ in,
                                        size_t mbase, int tid) {
    int l   = tid >> 3;
    int kc0 = (tid & 7) * 2;
    const float* g = in + (mbase + l) * Hc + (tid & 7) * 16;
    float4 f0 = *(const float4*)(g);
    float4 f1 = *(const float4*)(g + 4);
    float4 f2 = *(const float4*)(g + 8);
    float4 f3 = *(const float4*)(g + 12);
    short8 c0, c1;
    c0[0]=(short)f2bf(f0.x); c0[1]=(short)f2bf(f0.y); c0[2]=(short)f2bf(f0.z); c0[3]=(short)f2bf(f0.w);
    c0[4]=(short)f2bf(f1.x); c0[5]=(short)f2bf(f1.y); c0[6]=(short)f2bf(f1.z); c0[7]=(short)f2bf(f1.w);
    c1[0]=(short)f2bf(f2.x); c1[1]=(short)f2bf(f2.y); c1[2]=(short)f2bf(f2.z); c1[3]=(short)f2bf(f2.w);
    c1[4]=(short)f2bf(f3.x); c1[5]=(short)f2bf(f3.y); c1[6]=(short)f2bf(f3.z); c1[7]=(short)f2bf(f3.w);
    int sw = l & 7;
    *(short8*)(sm + LDS_U + l * 256 + (((kc0    ) ^ sw) << 4)) = c0;
    *(short8*)(sm + LDS_U + l * 256 + (((kc0 + 1) ^ sw) << 4)) = c1;
}

// ---------------------------------------------------------------- GEMM1 helper
__device__ __forceinline__ void gemm1_half(char* sm, const unsigned short* __restrict__ BF,
                                           int half, int wm, int wn, int lane,
                                           f32x4 (&acc)[2][4]) {
    int r = lane & 15, q = lane >> 4;
    #pragma unroll
    for (int i = 0; i < 2; i++)
        #pragma unroll
        for (int j = 0; j < 4; j++) acc[i][j] = (f32x4)(0.0f);
    #pragma unroll
    for (int kt = 0; kt < 4; ++kt) {
        short8 a[2];
        #pragma unroll
        for (int mf = 0; mf < 2; ++mf) {
            int la = wm * 32 + mf * 16 + r;
            int kc = kt * 4 + q;
            a[mf] = *(const short8*)(sm + LDS_U + la * 256 + ((kc ^ (la & 7)) << 4));
        }
        #pragma unroll
        for (int nfi = 0; nfi < 4; ++nfi) {
            int nfg = half * 16 + wn * 4 + nfi;
            short8 bb = *(const short8*)(BF + (size_t)((kt * 32 + nfg) * 64 + lane) * 8);
            acc[0][nfi] = mfma16(a[0], bb, acc[0][nfi]);
            acc[1][nfi] = mfma16(a[1], bb, acc[1][nfi]);
        }
    }
}

// ---------------------------------------------------------------- k_sum (pass1)
// GEMM1 + in-register weighted reduce: chunk-final = sum_l w[63-l] * bu_l.
__global__ __launch_bounds__(512, 6) void k_sum(const float* __restrict__ in,
                                                const unsigned short* __restrict__ BF,
                                                const float2* __restrict__ W,
                                                float2* __restrict__ loc) {
    __shared__ float4 smem4[LDSS_BYTES / 16];
    char* sm = (char*)smem4;
    float2* part = (float2*)(sm + LDS_PART);

    int tid  = threadIdx.x;
    int lane = tid & 63;
    int w    = tid >> 6;
    int wm   = w >> 2, wn = w & 3;
    int bc   = blockIdx.x;
    size_t mbase = (size_t)bc * CL;
    int r = lane & 15, q = lane >> 4;

    stage_U(sm, in, mbase, tid);
    __syncthreads();

    #pragma unroll
    for (int half = 0; half < 2; ++half) {
        f32x4 acc[2][4];
        gemm1_half(sm, BF, half, wm, wn, lane, acc);

        // weighted reduce over this lane's 8 l-values, per nfi channel
        float P1[4], P2[4];
        #pragma unroll
        for (int nfi = 0; nfi < 4; ++nfi) { P1[nfi] = 0.f; P2[nfi] = 0.f; }
        #pragma unroll
        for (int mf = 0; mf < 2; ++mf)
            #pragma unroll
            for (int j = 0; j < 4; ++j) {
                int l = wm * 32 + mf * 16 + q * 4 + j;
                #pragma unroll
                for (int nfi = 0; nfi < 4; ++nfi) {
                    int p = half * 128 + wn * 32 + nfi * 8 + (r >> 1);
                    float2 wv = W[p * CL + (CL - 1 - l)];
                    P1[nfi] = fmaf(wv.x, acc[mf][nfi][j], P1[nfi]);
                    P2[nfi] = fmaf(wv.y, acc[mf][nfi][j], P2[nfi]);
                }
            }
        // sum over q (lane bits 4,5)
        #pragma unroll
        for (int nfi = 0; nfi < 4; ++nfi) {
            P1[nfi] += __shfl_xor(P1[nfi], 16);
            P1[nfi] += __shfl_xor(P1[nfi], 32);
            P2[nfi] += __shfl_xor(P2[nfi], 16);
            P2[nfi] += __shfl_xor(P2[nfi], 32);
        }
        // cross-wm combine via LDS
        if (lane < 16) {
            #pragma unroll
            for (int nfi = 0; nfi < 4; ++nfi)
                part[wm * 256 + wn * 64 + nfi * 16 + r] = make_float2(P1[nfi], P2[nfi]);
        }
        __syncthreads();
        if (tid < 256) {
            float2 a = part[tid], b = part[256 + tid];
            loc[(size_t)bc * 512 + half * 256 + tid] = make_float2(a.x + b.x, a.y + b.y);
        }
        __syncthreads();
    }
}

// ---------------------------------------------------------------- k_pass2
__global__ __launch_bounds__(512, 6) void k_pass2(const float* __restrict__ in,
                                                  const float* __restrict__ cf,
                                                  const unsigned short* __restrict__ BF,
                                                  const unsigned short* __restrict__ CFr,
                                                  const float* __restrict__ Dw,
                                                  const float2* __restrict__ ini,
                                                  float* __restrict__ out) {
    __shared__ float4 smem4[LDS2_BYTES / 16];
    char* sm = (char*)smem4;
    char* bux = sm + LDS_BUX;

    int tid  = threadIdx.x;
    int lane = tid & 63;
    int w    = tid >> 6;
    int wm   = w >> 2, wn = w & 3;
    int bc   = blockIdx.x;
    size_t mbase = (size_t)bc * CL;
    int r = lane & 15, q = lane >> 4;

    stage_U(sm, in, mbase, tid);
    __syncthreads();

    f32x4 acc2[2][2];
    #pragma unroll
    for (int i = 0; i < 2; i++)
        #pragma unroll
        for (int j = 0; j < 2; j++) acc2[i][j] = (f32x4)(0.0f);

    #pragma unroll
    for (int half = 0; half < 2; ++half) {
        f32x4 acc[2][4];
        gemm1_half(sm, BF, half, wm, wn, lane, acc);

        __syncthreads();   // prev-half BUX readers (G2) done
        // acc -> BUX bf16, swizzled [64][256]
        #pragma unroll
        for (int mf = 0; mf < 2; ++mf)
            #pragma unroll
            for (int nfi = 0; nfi < 4; ++nfi) {
                int nn = wn * 64 + nfi * 16 + r;
                int kc = nn >> 3, e = nn & 7;
                #pragma unroll
                for (int j = 0; j < 4; ++j) {
                    int l = wm * 32 + mf * 16 + q * 4 + j;
                    *(unsigned short*)(bux + l * 512 + ((kc ^ swz(l)) << 4) + e * 2)
                        = f2bf(acc[mf][nfi][j]);
                }
            }
        __syncthreads();

        // scan: 256 threads, one channel each; in-place x2 bf16
        if (tid < 256) {
            int n = tid, ng = half * 256 + n, p = ng >> 1;
            float m11 = cf[p],        m12 = cf[256 + p];
            float m21 = cf[512 + p],  m22 = cf[768 + p];
            float s1  = cf[1024 + p], s2  = cf[1280 + p];
            float2 iv = ini[(size_t)bc * 512 + ng];
            float x1 = iv.x, x2 = iv.y;
            char* bp = bux + (n & 7) * 2;
            int kc = n >> 3;
            #pragma unroll 4
            for (int l = 0; l < CL; ++l) {
                char* addr = bp + l * 512 + ((kc ^ swz(l)) << 4);
                float f  = bf2f(*(unsigned short*)addr);
                float n1 = fmaf(m11, x1, fmaf(m12, x2, s1 * f));
                float n2 = fmaf(m21, x1, fmaf(m22, x2, s2 * f));
                x1 = n1; x2 = n2;
                *(unsigned short*)addr = f2bf(x2);
            }
        }
        __syncthreads();

        // GEMM2 partial over this half's 256 channels
        #pragma unroll
        for (int kt = 0; kt < 8; ++kt) {
            short8 a2[2];
            #pragma unroll
            for (int mf = 0; mf < 2; ++mf) {
                int la  = wm * 32 + mf * 16 + r;
                int kc2 = kt * 4 + q;
                a2[mf] = *(const short8*)(bux + la * 512 + ((kc2 ^ swz(la)) << 4));
            }
            #pragma unroll
            for (int nfi = 0; nfi < 2; ++nfi) {
                int ktG = half * 8 + kt;
                int nfg = wn * 2 + nfi;
                short8 bb = *(const short8*)(CFr + (size_t)((ktG * 8 + nfg) * 64 + lane) * 8);
                acc2[0][nfi] = mfma16(a2[0], bb, acc2[0][nfi]);
                acc2[1][nfi] = mfma16(a2[1], bb, acc2[1][nfi]);
            }
        }
    }

    // epilogue: out = acc2 + in*D
    #pragma unroll
    for (int nfi = 0; nfi < 2; ++nfi) {
        int h = wn * 32 + nfi * 16 + r;
        float d = Dw[h];
        #pragma unroll
        for (int mf = 0; mf < 2; ++mf)
            #pragma unroll
            for (int j = 0; j < 4; ++j) {
                int l = wm * 32 + mf * 16 + q * 4 + j;
                size_t gm = mbase + l;
                out[gm * Hc + h] = fmaf(in[gm * Hc + h], d, acc2[mf][nfi][j]);
            }
    }
}

// ---------------------------------------------------------------- launch
extern "C" void kernel_launch(void* const* d_in, const int* in_sizes, int n_in,
                              void* d_out, int out_size, void* d_ws, size_t ws_size,
                              hipStream_t stream) {
    const float* in  = (const float*)d_in[0];
    const float* Ad  = (const float*)d_in[1];
    const float* Bw  = (const float*)d_in[2];
    const float* Cw  = (const float*)d_in[3];
    const float* Dw  = (const float*)d_in[4];
    const float* stp = (const float*)d_in[5];
    char* ws = (char*)d_ws;
    float*          cf  = (float*)(ws + CF_OFF);
    unsigned short* BF  = (unsigned short*)(ws + BF_OFF);
    unsigned short* CFr = (unsigned short*)(ws + CFR_OFF);
    float2*         W   = (float2*)(ws + W_OFF);
    float2*         loc = (float2*)(ws + LOC_OFF);
    float2*         ini = (float2*)(ws + INI_OFF);
    float* out = (float*)d_out;

    k_prep<<<256, 256, 0, stream>>>(Ad, stp, Bw, Cw, cf, BF, CFr, W);
    k_sum<<<BTc * NC, 512, 0, stream>>>(in, BF, W, loc);
    k_scanB<<<BTc, 512, 0, stream>>>(cf, loc, ini);
    k_pass2<<<BTc * NC, 512, 0, stream>>>(in, cf, BF, CFr, Dw, ini, out);
}